// Round 13
// baseline (226.504 us; speedup 1.0000x reference)
//
#include <hip/hip_runtime.h>

// 2-layer GCN, 6 launches:
// gemm1(+zero cnt/flags+W2cvt extras) -> cnt(int4) ->
// sfd(scan|fill|degsum, spin-fused 256 blocks) -> agg1 -> gemm2 -> agg2

constexpr int SCAN_BLOCKS = 256;

typedef __attribute__((ext_vector_type(8))) short short8;   // 8 bf16
typedef __attribute__((ext_vector_type(4))) float f32x4;

__device__ __forceinline__ ushort f2bf(float f) {           // RNE f32->bf16
    unsigned u = __float_as_uint(f);
    return (ushort)((u + 0x7fffu + ((u >> 16) & 1u)) >> 16);
}
__device__ __forceinline__ float bf2f(ushort h) {
    return __uint_as_float((unsigned)h << 16);
}

// device-scope grid barrier for a 256-block resident grid (1 block/CU).
// release: threadfence (L2 writeback) + device-scope atomicAdd;
// acquire: spin + threadfence (L1/L2 invalidate).
__device__ __forceinline__ void grid_bar(int* flag, int target) {
    __syncthreads();
    if (threadIdx.x == 0) {
        __threadfence();
        atomicAdd(flag, 1);
        while (__hip_atomic_load(flag, __ATOMIC_RELAXED,
                                 __HIP_MEMORY_SCOPE_AGENT) < target) {}
    }
    __syncthreads();
    __threadfence();
}

// ======== gemm1: Ab = bf16(X @ W1); extras zero cnt+flags & convert W2t ====
__global__ __launch_bounds__(256, 2) void gemm1_kernel(
        const float* __restrict__ X, const float* __restrict__ W1,
        ushort* __restrict__ Ab, int N, int G,
        int* __restrict__ cnt, const float* __restrict__ W2,
        ushort* __restrict__ W2t) {
    __shared__ __align__(16) ushort sX[128 * 128];
    __shared__ __align__(16) ushort sW[128 * 128];
    const int tid = threadIdx.x;

    if (blockIdx.x >= G) {                 // throughput-bound extras only
        const int b = blockIdx.x - G;
        const int n4 = (N >> 2) + 1;       // covers cnt[0..N+3] (incl. flags)
        const int nbz = (n4 + 255) / 256;
        if (b < nbz) {
            const int i = b * 256 + tid;
            if (i < n4) reinterpret_cast<int4*>(cnt)[i] = make_int4(0, 0, 0, 0);
        } else {
            const int o = (b - nbz) * 256 + tid;   // W2t[c*128+k] = W2[k*64+c]
            if (o < 64 * 128)
                W2t[o] = f2bf(W2[(size_t)(o & 127) * 64 + (o >> 7)]);
        }
        return;
    }

    const int base = blockIdx.x * 128;
    #pragma unroll
    for (int p = 0; p < 8; p++) {          // X f32 -> bf16, swizzled
        const int ch = p * 256 + tid;
        const int r = ch >> 4, cpos = ch & 15;
        const int grow = base + r;
        uint4 u = make_uint4(0, 0, 0, 0);
        if (grow < N) {
            const float* xp = X + (size_t)grow * 128 + cpos * 8;
            const float4 a = *reinterpret_cast<const float4*>(xp);
            const float4 c = *reinterpret_cast<const float4*>(xp + 4);
            u.x = (uint)f2bf(a.x) | ((uint)f2bf(a.y) << 16);
            u.y = (uint)f2bf(a.z) | ((uint)f2bf(a.w) << 16);
            u.z = (uint)f2bf(c.x) | ((uint)f2bf(c.y) << 16);
            u.w = (uint)f2bf(c.z) | ((uint)f2bf(c.w) << 16);
        }
        const int b = (cpos * 16) ^ ((r & 7) << 4);
        *reinterpret_cast<uint4*>(reinterpret_cast<char*>(sX) + r * 256 + b) = u;
    }
    #pragma unroll
    for (int p = 0; p < 8; p++) {          // W1[k][c] f32 -> sW[c][k] bf16 swz
        const int ch = p * 256 + tid;
        const int c = ch & 127, kc = ch >> 7;
        const int k0 = kc * 8;
        float f[8];
        #pragma unroll
        for (int j = 0; j < 8; j++) f[j] = W1[(size_t)(k0 + j) * 128 + c];
        uint4 u;
        u.x = (uint)f2bf(f[0]) | ((uint)f2bf(f[1]) << 16);
        u.y = (uint)f2bf(f[2]) | ((uint)f2bf(f[3]) << 16);
        u.z = (uint)f2bf(f[4]) | ((uint)f2bf(f[5]) << 16);
        u.w = (uint)f2bf(f[6]) | ((uint)f2bf(f[7]) << 16);
        const int b = (k0 * 2) ^ ((c & 7) << 4);
        *reinterpret_cast<uint4*>(reinterpret_cast<char*>(sW) + c * 256 + b) = u;
    }
    __syncthreads();

    const int lane = tid & 63;
    const int wid = tid >> 6;
    const int wr = wid >> 1;               // 2 row-waves
    const int wc = wid & 1;                // 2 col-waves
    const int lr = lane & 15;
    const int g  = lane >> 4;

    f32x4 acc[4][4];
    #pragma unroll
    for (int i = 0; i < 4; i++)
        #pragma unroll
        for (int f = 0; f < 4; f++) acc[i][f] = (f32x4){0.f, 0.f, 0.f, 0.f};

    #pragma unroll
    for (int ks = 0; ks < 4; ks++) {
        const int koff = ks * 64 + g * 16;
        short8 a[4], b[4];
        #pragma unroll
        for (int i = 0; i < 4; i++) {
            const int r = wr * 64 + i * 16 + lr;
            a[i] = *reinterpret_cast<const short8*>(
                reinterpret_cast<const char*>(sX) + r * 256 + (koff ^ ((r & 7) << 4)));
        }
        #pragma unroll
        for (int f = 0; f < 4; f++) {
            const int c = wc * 64 + f * 16 + lr;
            b[f] = *reinterpret_cast<const short8*>(
                reinterpret_cast<const char*>(sW) + c * 256 + (koff ^ ((c & 7) << 4)));
        }
        #pragma unroll
        for (int i = 0; i < 4; i++)
            #pragma unroll
            for (int f = 0; f < 4; f++)
                acc[i][f] = __builtin_amdgcn_mfma_f32_16x16x32_bf16(a[i], b[f], acc[i][f], 0, 0, 0);
    }

    #pragma unroll
    for (int i = 0; i < 4; i++)
        #pragma unroll
        for (int reg = 0; reg < 4; reg++) {
            const int grow = base + wr * 64 + i * 16 + g * 4 + reg;
            if (grow < N)
                #pragma unroll
                for (int f = 0; f < 4; f++)
                    Ab[(size_t)grow * 128 + wc * 64 + f * 16 + lr] = f2bf(acc[i][f][reg]);
        }
}

// ======== histogram + rank (int4, 4 edges/thread, full occupancy) ========
__global__ void cnt_kernel(const int* __restrict__ col, int* __restrict__ cnt,
                           int* __restrict__ rank, int E) {
    const int e4 = (blockIdx.x * blockDim.x + threadIdx.x) * 4;
    if (e4 + 3 < E) {
        const int4 c4 = *reinterpret_cast<const int4*>(col + e4);
        int4 r4;
        r4.x = atomicAdd(&cnt[c4.x], 1);
        r4.y = atomicAdd(&cnt[c4.y], 1);
        r4.z = atomicAdd(&cnt[c4.z], 1);
        r4.w = atomicAdd(&cnt[c4.w], 1);
        *reinterpret_cast<int4*>(rank + e4) = r4;
    } else {
        for (int e = e4; e < E; e++) rank[e] = atomicAdd(&cnt[col[e]], 1);
    }
}

// ======== sfd: scan -> [bar] -> rowptr -> [bar] -> fill -> [bar] -> degsum ==
__global__ __launch_bounds__(256) void sfd_kernel(
        const int* __restrict__ cnt, int* __restrict__ rowptr,
        int* __restrict__ partial, int* __restrict__ flags,
        const int* __restrict__ row, const int* __restrict__ col,
        const float* __restrict__ ew, const int* __restrict__ rank,
        int2* __restrict__ csr, float* __restrict__ dinv, int N, int E) {
    const int t = threadIdx.x, b = blockIdx.x;
    const int T = SCAN_BLOCKS * 256;
    const int gtid = b * 256 + t;
    const int chunk = (N + T - 1) / T;
    const int s = min(gtid * chunk, N), e = min(s + chunk, N);

    // phase 1: per-thread chunk sum, block scan, partial[b]
    int acc = 0;
    for (int i = s; i < e; i++) acc += cnt[i];
    __shared__ int sh[256];
    sh[t] = acc;
    __syncthreads();
    for (int off = 1; off < 256; off <<= 1) {
        int x = sh[t];
        int a = (t >= off) ? sh[t - off] : 0;
        __syncthreads();
        sh[t] = x + a;
        __syncthreads();
    }
    const int thr_excl = sh[t] - acc;
    if (t == 255) partial[b] = sh[255];
    grid_bar(&flags[0], SCAN_BLOCKS);

    // phase 2: scan partials, write rowptr chunk
    __shared__ int tp[256];
    tp[t] = partial[t];
    __syncthreads();
    for (int off = 1; off < 256; off <<= 1) {
        int x = tp[t];
        int a = (t >= off) ? tp[t - off] : 0;
        __syncthreads();
        tp[t] = x + a;
        __syncthreads();
    }
    int run = ((b == 0) ? 0 : tp[b - 1]) + thr_excl;
    for (int i = s; i < e; i++) { rowptr[i] = run; run += cnt[i]; }
    if (gtid == 0) rowptr[N] = E;
    grid_bar(&flags[1], SCAN_BLOCKS);

    // phase 3: fill CSR {src, raw ew}; int4 4-edge groups, grid-stride
    const int ngrp = (E + 3) >> 2;
    for (int g = gtid; g < ngrp; g += T) {
        const int e4 = g * 4;
        if (e4 + 3 < E) {
            const int4 c4 = *reinterpret_cast<const int4*>(col + e4);
            const int4 r4 = *reinterpret_cast<const int4*>(row + e4);
            const int4 w4 = *reinterpret_cast<const int4*>((const int*)ew + e4);
            const int4 k4 = *reinterpret_cast<const int4*>(rank + e4);
            const int p0 = rowptr[c4.x] + k4.x;
            const int p1 = rowptr[c4.y] + k4.y;
            const int p2 = rowptr[c4.z] + k4.z;
            const int p3 = rowptr[c4.w] + k4.w;
            csr[p0] = make_int2(r4.x, w4.x);
            csr[p1] = make_int2(r4.y, w4.y);
            csr[p2] = make_int2(r4.z, w4.z);
            csr[p3] = make_int2(r4.w, w4.w);
        } else {
            for (int ee = e4; ee < E; ee++)
                csr[rowptr[col[ee]] + rank[ee]] =
                    make_int2(row[ee], __float_as_int(ew[ee]));
        }
    }
    grid_bar(&flags[2], SCAN_BLOCKS);

    // phase 4: degsum -> dinv
    for (int n = gtid; n < N; n += T) {
        const int e0 = rowptr[n], e1 = rowptr[n + 1];
        float d = 1.0f;
        for (int k = e0; k < e1; k++) d += __int_as_float(csr[k].y);
        dinv[n] = (d > 0.0f) ? rsqrtf(d) : 0.0f;
    }
}

// ======== agg1: Hb = relu(Ahat@Ab + b1); 16 lanes/node, 4-wide MLP ========
__global__ __launch_bounds__(256) void agg1_kernel(
        const int* __restrict__ rowptr, const int2* __restrict__ csr,
        const float* __restrict__ dinv,
        const ushort* __restrict__ src, const float* __restrict__ bias,
        ushort* __restrict__ dst, int N) {
    const int gid = blockIdx.x * 256 + threadIdx.x;
    const int c = gid >> 4;
    if (c >= N) return;
    const int lane = gid & 15;
    const float di = dinv[c];
    const float sl = di * di;
    float acc[8];
    {
        const short8 s8 = *reinterpret_cast<const short8*>(src + (size_t)c * 128 + lane * 8);
        #pragma unroll
        for (int j = 0; j < 8; j++) acc[j] = bf2f((ushort)s8[j]) * sl;
    }
    const int e0 = rowptr[c], e1 = rowptr[c + 1];
    int e = e0;
    for (; e + 4 <= e1; e += 4) {
        const int2 c0 = csr[e], c1 = csr[e + 1], c2 = csr[e + 2], c3 = csr[e + 3];
        const float w0 = __int_as_float(c0.y) * dinv[c0.x] * di;
        const float w1 = __int_as_float(c1.y) * dinv[c1.x] * di;
        const float w2 = __int_as_float(c2.y) * dinv[c2.x] * di;
        const float w3 = __int_as_float(c3.y) * dinv[c3.x] * di;
        const short8 v0 = *reinterpret_cast<const short8*>(src + (size_t)c0.x * 128 + lane * 8);
        const short8 v1 = *reinterpret_cast<const short8*>(src + (size_t)c1.x * 128 + lane * 8);
        const short8 v2 = *reinterpret_cast<const short8*>(src + (size_t)c2.x * 128 + lane * 8);
        const short8 v3 = *reinterpret_cast<const short8*>(src + (size_t)c3.x * 128 + lane * 8);
        #pragma unroll
        for (int j = 0; j < 8; j++)
            acc[j] += bf2f((ushort)v0[j]) * w0 + bf2f((ushort)v1[j]) * w1 +
                      bf2f((ushort)v2[j]) * w2 + bf2f((ushort)v3[j]) * w3;
    }
    for (; e < e1; e++) {
        const int2 ce = csr[e];
        const float w = __int_as_float(ce.y) * dinv[ce.x] * di;
        const short8 v = *reinterpret_cast<const short8*>(src + (size_t)ce.x * 128 + lane * 8);
        #pragma unroll
        for (int j = 0; j < 8; j++) acc[j] += bf2f((ushort)v[j]) * w;
    }
    const float4 b0 = reinterpret_cast<const float4*>(bias)[lane * 2];
    const float4 b1 = reinterpret_cast<const float4*>(bias)[lane * 2 + 1];
    acc[0] = fmaxf(acc[0] + b0.x, 0.f); acc[1] = fmaxf(acc[1] + b0.y, 0.f);
    acc[2] = fmaxf(acc[2] + b0.z, 0.f); acc[3] = fmaxf(acc[3] + b0.w, 0.f);
    acc[4] = fmaxf(acc[4] + b1.x, 0.f); acc[5] = fmaxf(acc[5] + b1.y, 0.f);
    acc[6] = fmaxf(acc[6] + b1.z, 0.f); acc[7] = fmaxf(acc[7] + b1.w, 0.f);
    uint4 o;
    o.x = (uint)f2bf(acc[0]) | ((uint)f2bf(acc[1]) << 16);
    o.y = (uint)f2bf(acc[2]) | ((uint)f2bf(acc[3]) << 16);
    o.z = (uint)f2bf(acc[4]) | ((uint)f2bf(acc[5]) << 16);
    o.w = (uint)f2bf(acc[6]) | ((uint)f2bf(acc[7]) << 16);
    *reinterpret_cast<uint4*>(dst + (size_t)c * 128 + lane * 8) = o;
}

// ======== gemm2: Gb = bf16(Hb @ W2t^T), DOUT=64 ========
__global__ __launch_bounds__(256, 2) void gemm2_kernel(
        const ushort* __restrict__ Xb, const ushort* __restrict__ Wt,
        ushort* __restrict__ Y, int N) {
    __shared__ __align__(16) ushort sX[128 * 128];
    __shared__ __align__(16) ushort sW[64 * 128];
    const int tid = threadIdx.x;
    const int base = blockIdx.x * 128;

    #pragma unroll
    for (int p = 0; p < 8; p++) {
        const int ch = p * 256 + tid;
        const int r = ch >> 4, cpos = ch & 15;
        const int grow = base + r;
        uint4 v = make_uint4(0, 0, 0, 0);
        if (grow < N)
            v = *reinterpret_cast<const uint4*>(Xb + (size_t)grow * 128 + cpos * 8);
        const int b = (cpos * 16) ^ ((r & 7) << 4);
        *reinterpret_cast<uint4*>(reinterpret_cast<char*>(sX) + r * 256 + b) = v;
    }
    #pragma unroll
    for (int p = 0; p < 4; p++) {
        const int ch = p * 256 + tid;
        const int r = ch >> 4, cpos = ch & 15;
        uint4 v = *reinterpret_cast<const uint4*>(Wt + (size_t)r * 128 + cpos * 8);
        const int b = (cpos * 16) ^ ((r & 7) << 4);
        *reinterpret_cast<uint4*>(reinterpret_cast<char*>(sW) + r * 256 + b) = v;
    }
    __syncthreads();

    const int lane = tid & 63;
    const int wid = tid >> 6;              // 4 row-waves, 1 col-wave
    const int lr = lane & 15;
    const int g  = lane >> 4;

    f32x4 acc[2][4];
    #pragma unroll
    for (int i = 0; i < 2; i++)
        #pragma unroll
        for (int f = 0; f < 4; f++) acc[i][f] = (f32x4){0.f, 0.f, 0.f, 0.f};

    #pragma unroll
    for (int ks = 0; ks < 4; ks++) {
        const int koff = ks * 64 + g * 16;
        short8 a[2], b[4];
        #pragma unroll
        for (int i = 0; i < 2; i++) {
            const int r = wid * 32 + i * 16 + lr;
            a[i] = *reinterpret_cast<const short8*>(
                reinterpret_cast<const char*>(sX) + r * 256 + (koff ^ ((r & 7) << 4)));
        }
        #pragma unroll
        for (int f = 0; f < 4; f++) {
            const int c = f * 16 + lr;
            b[f] = *reinterpret_cast<const short8*>(
                reinterpret_cast<const char*>(sW) + c * 256 + (koff ^ ((c & 7) << 4)));
        }
        #pragma unroll
        for (int i = 0; i < 2; i++)
            #pragma unroll
            for (int f = 0; f < 4; f++)
                acc[i][f] = __builtin_amdgcn_mfma_f32_16x16x32_bf16(a[i], b[f], acc[i][f], 0, 0, 0);
    }

    #pragma unroll
    for (int i = 0; i < 2; i++)
        #pragma unroll
        for (int reg = 0; reg < 4; reg++) {
            const int grow = base + wid * 32 + i * 16 + g * 4 + reg;
            if (grow < N)
                #pragma unroll
                for (int f = 0; f < 4; f++)
                    Y[(size_t)grow * 64 + f * 16 + lr] = f2bf(acc[i][f][reg]);
        }
}

// ======== agg2: out f32 = Ahat @ Gb + b2 (8 lanes/node) ========
__global__ __launch_bounds__(256) void agg2_kernel(
        const int* __restrict__ rowptr, const int2* __restrict__ csr,
        const float* __restrict__ dinv,
        const ushort* __restrict__ src, const float* __restrict__ bias,
        float* __restrict__ dst, int N) {
    const int gid = blockIdx.x * 256 + threadIdx.x;
    const int c = gid >> 3;
    if (c >= N) return;
    const int lane = gid & 7;
    const float di = dinv[c];
    const float sl = di * di;
    float acc[8];
    {
        const short8 s8 = *reinterpret_cast<const short8*>(src + (size_t)c * 64 + lane * 8);
        #pragma unroll
        for (int j = 0; j < 8; j++) acc[j] = bf2f((ushort)s8[j]) * sl;
    }
    const int e0 = rowptr[c], e1 = rowptr[c + 1];
    int e = e0;
    for (; e + 4 <= e1; e += 4) {
        const int2 c0 = csr[e], c1 = csr[e + 1], c2 = csr[e + 2], c3 = csr[e + 3];
        const float w0 = __int_as_float(c0.y) * dinv[c0.x] * di;
        const float w1 = __int_as_float(c1.y) * dinv[c1.x] * di;
        const float w2 = __int_as_float(c2.y) * dinv[c2.x] * di;
        const float w3 = __int_as_float(c3.y) * dinv[c3.x] * di;
        const short8 v0 = *reinterpret_cast<const short8*>(src + (size_t)c0.x * 64 + lane * 8);
        const short8 v1 = *reinterpret_cast<const short8*>(src + (size_t)c1.x * 64 + lane * 8);
        const short8 v2 = *reinterpret_cast<const short8*>(src + (size_t)c2.x * 64 + lane * 8);
        const short8 v3 = *reinterpret_cast<const short8*>(src + (size_t)c3.x * 64 + lane * 8);
        #pragma unroll
        for (int j = 0; j < 8; j++)
            acc[j] += bf2f((ushort)v0[j]) * w0 + bf2f((ushort)v1[j]) * w1 +
                      bf2f((ushort)v2[j]) * w2 + bf2f((ushort)v3[j]) * w3;
    }
    for (; e < e1; e++) {
        const int2 ce = csr[e];
        const float w = __int_as_float(ce.y) * dinv[ce.x] * di;
        const short8 v = *reinterpret_cast<const short8*>(src + (size_t)ce.x * 64 + lane * 8);
        #pragma unroll
        for (int j = 0; j < 8; j++) acc[j] += bf2f((ushort)v[j]) * w;
    }
    const float4 b0 = reinterpret_cast<const float4*>(bias)[lane * 2];
    const float4 b1 = reinterpret_cast<const float4*>(bias)[lane * 2 + 1];
    float* dp = dst + (size_t)c * 64 + lane * 8;
    *reinterpret_cast<float4*>(dp) =
        make_float4(acc[0] + b0.x, acc[1] + b0.y, acc[2] + b0.z, acc[3] + b0.w);
    *reinterpret_cast<float4*>(dp + 4) =
        make_float4(acc[4] + b1.x, acc[5] + b1.y, acc[6] + b1.z, acc[7] + b1.w);
}

extern "C" void kernel_launch(void* const* d_in, const int* in_sizes, int n_in,
                              void* d_out, int out_size, void* d_ws, size_t ws_size,
                              hipStream_t stream) {
    const float* x  = (const float*)d_in[0];
    const int*   ei = (const int*)d_in[1];
    const float* ew = (const float*)d_in[2];
    const float* W1 = (const float*)d_in[3];
    const float* b1 = (const float*)d_in[4];
    const float* W2 = (const float*)d_in[5];
    const float* b2 = (const float*)d_in[6];
    const int N = in_sizes[0] / 128;
    const int E = in_sizes[1] / 2;
    const int* row = ei;
    const int* col = ei + E;

    char* w = (char*)d_ws;
    float* dinv = (float*)w;                 w += (size_t)N * 4;
    ushort* Ab  = (ushort*)w;                w += (size_t)N * 256;  // bf16 xw
    ushort* Hb  = (ushort*)w;                w += (size_t)N * 256;  // bf16 h
    ushort* Gb  = (ushort*)w;                w += (size_t)N * 128;  // bf16 hw
    ushort* W2t = (ushort*)w;                w += 64 * 128 * 2;
    int* cnt    = (int*)w;                   w += (size_t)N * 4 + 16;  // +flags
    int* rowptr = (int*)w;                   w += (size_t)(N + 8) * 4;
    int* partial= (int*)w;                   w += 2048 * 4;
    int* rank   = (int*)w;                   w += (size_t)E * 4;
    int2* csr   = (int2*)w;
    float* out  = (float*)d_out;
    int* flags  = cnt + N;                   // 3 flags, zeroed by gemm1 extras

    const int ntiles = (N + 127) / 128;
    const int nbz = ((N >> 2) + 1 + 255) / 256;
    const int eb4 = (E / 4 + 255) / 256;

    gemm1_kernel<<<ntiles + nbz + 32, 256, 0, stream>>>(x, W1, Ab, N, ntiles,
                                                        cnt, W2, W2t);
    cnt_kernel<<<eb4, 256, 0, stream>>>(col, cnt, rank, E);
    sfd_kernel<<<SCAN_BLOCKS, 256, 0, stream>>>(cnt, rowptr, partial, flags,
                                                row, col, ew, rank, csr, dinv, N, E);
    agg1_kernel<<<(N * 16 + 255) / 256, 256, 0, stream>>>(rowptr, csr, dinv, Ab, b1, Hb, N);
    gemm2_kernel<<<ntiles, 256, 0, stream>>>(Hb, W2t, Gb, N);
    agg2_kernel<<<(N * 8 + 255) / 256, 256, 0, stream>>>(rowptr, csr, dinv, Gb, b2, out, N);
}

// Round 14
// 135.458 us; speedup vs baseline: 1.6721x; 1.6721x over previous
//
#include <hip/hip_runtime.h>

// 2-layer GCN, 9 discrete launches (empirically fastest structure):
// gemm1(+zero cnt/flags+W2cvt extras) -> cnt(int4) -> scan_part ->
// scan_write -> fill(int4) -> degsum -> agg1 -> gemm2 -> agg2

constexpr int SCAN_BLOCKS = 256;

typedef __attribute__((ext_vector_type(8))) short short8;   // 8 bf16
typedef __attribute__((ext_vector_type(4))) float f32x4;

__device__ __forceinline__ ushort f2bf(float f) {           // RNE f32->bf16
    unsigned u = __float_as_uint(f);
    return (ushort)((u + 0x7fffu + ((u >> 16) & 1u)) >> 16);
}
__device__ __forceinline__ float bf2f(ushort h) {
    return __uint_as_float((unsigned)h << 16);
}

// ======== gemm1: Ab = bf16(X @ W1); extras zero cnt & convert W2t ========
__global__ __launch_bounds__(256, 2) void gemm1_kernel(
        const float* __restrict__ X, const float* __restrict__ W1,
        ushort* __restrict__ Ab, int N, int G,
        int* __restrict__ cnt, const float* __restrict__ W2,
        ushort* __restrict__ W2t) {
    __shared__ __align__(16) ushort sX[128 * 128];
    __shared__ __align__(16) ushort sW[128 * 128];
    const int tid = threadIdx.x;

    if (blockIdx.x >= G) {                 // throughput-bound extras only
        const int b = blockIdx.x - G;
        const int n4 = (N >> 2) + 1;
        const int nbz = (n4 + 255) / 256;
        if (b < nbz) {
            const int i = b * 256 + tid;
            if (i < n4) reinterpret_cast<int4*>(cnt)[i] = make_int4(0, 0, 0, 0);
        } else {
            const int o = (b - nbz) * 256 + tid;   // W2t[c*128+k] = W2[k*64+c]
            if (o < 64 * 128)
                W2t[o] = f2bf(W2[(size_t)(o & 127) * 64 + (o >> 7)]);
        }
        return;
    }

    const int base = blockIdx.x * 128;
    #pragma unroll
    for (int p = 0; p < 8; p++) {          // X f32 -> bf16, swizzled
        const int ch = p * 256 + tid;
        const int r = ch >> 4, cpos = ch & 15;
        const int grow = base + r;
        uint4 u = make_uint4(0, 0, 0, 0);
        if (grow < N) {
            const float* xp = X + (size_t)grow * 128 + cpos * 8;
            const float4 a = *reinterpret_cast<const float4*>(xp);
            const float4 c = *reinterpret_cast<const float4*>(xp + 4);
            u.x = (uint)f2bf(a.x) | ((uint)f2bf(a.y) << 16);
            u.y = (uint)f2bf(a.z) | ((uint)f2bf(a.w) << 16);
            u.z = (uint)f2bf(c.x) | ((uint)f2bf(c.y) << 16);
            u.w = (uint)f2bf(c.z) | ((uint)f2bf(c.w) << 16);
        }
        const int b = (cpos * 16) ^ ((r & 7) << 4);
        *reinterpret_cast<uint4*>(reinterpret_cast<char*>(sX) + r * 256 + b) = u;
    }
    #pragma unroll
    for (int p = 0; p < 8; p++) {          // W1[k][c] f32 -> sW[c][k] bf16 swz
        const int ch = p * 256 + tid;
        const int c = ch & 127, kc = ch >> 7;
        const int k0 = kc * 8;
        float f[8];
        #pragma unroll
        for (int j = 0; j < 8; j++) f[j] = W1[(size_t)(k0 + j) * 128 + c];
        uint4 u;
        u.x = (uint)f2bf(f[0]) | ((uint)f2bf(f[1]) << 16);
        u.y = (uint)f2bf(f[2]) | ((uint)f2bf(f[3]) << 16);
        u.z = (uint)f2bf(f[4]) | ((uint)f2bf(f[5]) << 16);
        u.w = (uint)f2bf(f[6]) | ((uint)f2bf(f[7]) << 16);
        const int b = (k0 * 2) ^ ((c & 7) << 4);
        *reinterpret_cast<uint4*>(reinterpret_cast<char*>(sW) + c * 256 + b) = u;
    }
    __syncthreads();

    const int lane = tid & 63;
    const int wid = tid >> 6;
    const int wr = wid >> 1;               // 2 row-waves
    const int wc = wid & 1;                // 2 col-waves
    const int lr = lane & 15;
    const int g  = lane >> 4;

    f32x4 acc[4][4];
    #pragma unroll
    for (int i = 0; i < 4; i++)
        #pragma unroll
        for (int f = 0; f < 4; f++) acc[i][f] = (f32x4){0.f, 0.f, 0.f, 0.f};

    #pragma unroll
    for (int ks = 0; ks < 4; ks++) {
        const int koff = ks * 64 + g * 16;
        short8 a[4], b[4];
        #pragma unroll
        for (int i = 0; i < 4; i++) {
            const int r = wr * 64 + i * 16 + lr;
            a[i] = *reinterpret_cast<const short8*>(
                reinterpret_cast<const char*>(sX) + r * 256 + (koff ^ ((r & 7) << 4)));
        }
        #pragma unroll
        for (int f = 0; f < 4; f++) {
            const int c = wc * 64 + f * 16 + lr;
            b[f] = *reinterpret_cast<const short8*>(
                reinterpret_cast<const char*>(sW) + c * 256 + (koff ^ ((c & 7) << 4)));
        }
        #pragma unroll
        for (int i = 0; i < 4; i++)
            #pragma unroll
            for (int f = 0; f < 4; f++)
                acc[i][f] = __builtin_amdgcn_mfma_f32_16x16x32_bf16(a[i], b[f], acc[i][f], 0, 0, 0);
    }

    #pragma unroll
    for (int i = 0; i < 4; i++)
        #pragma unroll
        for (int reg = 0; reg < 4; reg++) {
            const int grow = base + wr * 64 + i * 16 + g * 4 + reg;
            if (grow < N)
                #pragma unroll
                for (int f = 0; f < 4; f++)
                    Ab[(size_t)grow * 128 + wc * 64 + f * 16 + lr] = f2bf(acc[i][f][reg]);
        }
}

// ======== histogram + rank (int4, 4 edges/thread, full occupancy) ========
__global__ void cnt_kernel(const int* __restrict__ col, int* __restrict__ cnt,
                           int* __restrict__ rank, int E) {
    const int e4 = (blockIdx.x * blockDim.x + threadIdx.x) * 4;
    if (e4 + 3 < E) {
        const int4 c4 = *reinterpret_cast<const int4*>(col + e4);
        int4 r4;
        r4.x = atomicAdd(&cnt[c4.x], 1);
        r4.y = atomicAdd(&cnt[c4.y], 1);
        r4.z = atomicAdd(&cnt[c4.z], 1);
        r4.w = atomicAdd(&cnt[c4.w], 1);
        *reinterpret_cast<int4*>(rank + e4) = r4;
    } else {
        for (int e = e4; e < E; e++) rank[e] = atomicAdd(&cnt[col[e]], 1);
    }
}

// ======== 2-pass scan (discrete, proven) ========
__global__ __launch_bounds__(256) void scan_part_kernel(
        const int* __restrict__ cnt, int* __restrict__ partial, int N) {
    const int T = SCAN_BLOCKS * 256;
    const int chunk = (N + T - 1) / T;
    const int j = blockIdx.x * 256 + threadIdx.x;
    const int s = j * chunk, e = min(s + chunk, N);
    int acc = 0;
    for (int i = s; i < e; i++) acc += cnt[i];
    __shared__ int red[256];
    red[threadIdx.x] = acc;
    __syncthreads();
    for (int off = 128; off > 0; off >>= 1) {
        if (threadIdx.x < off) red[threadIdx.x] += red[threadIdx.x + off];
        __syncthreads();
    }
    if (threadIdx.x == 0) partial[blockIdx.x] = red[0];
}

__global__ __launch_bounds__(256) void scan_write_kernel(
        const int* __restrict__ cnt, const int* __restrict__ partial,
        int* __restrict__ rowptr, int N, int E) {
    __shared__ int tp[256];
    __shared__ int sh[256];
    const int t = threadIdx.x;
    tp[t] = partial[t];
    __syncthreads();
    for (int off = 1; off < 256; off <<= 1) {
        int x = tp[t];
        int a = (t >= off) ? tp[t - off] : 0;
        __syncthreads();
        tp[t] = x + a;
        __syncthreads();
    }
    const int blockOff = (blockIdx.x == 0) ? 0 : tp[blockIdx.x - 1];
    const int T = SCAN_BLOCKS * 256;
    const int chunk = (N + T - 1) / T;
    const int j = blockIdx.x * 256 + t;
    const int s = j * chunk, e = min(s + chunk, N);
    int acc = 0;
    for (int i = s; i < e; i++) acc += cnt[i];
    sh[t] = acc;
    __syncthreads();
    for (int off = 1; off < 256; off <<= 1) {
        int x = sh[t];
        int a = (t >= off) ? sh[t - off] : 0;
        __syncthreads();
        sh[t] = x + a;
        __syncthreads();
    }
    int excl = blockOff + ((t == 0) ? 0 : sh[t - 1]);
    for (int i = s; i < e; i++) { rowptr[i] = excl; excl += cnt[i]; }
    if (j == 0) rowptr[N] = E;
}

// ======== fill CSR {src, raw ew}: int4 4-edge unroll (MLP) ========
__global__ void fill_kernel(const int* __restrict__ row, const int* __restrict__ col,
        const float* __restrict__ ew, const int* __restrict__ rowptr,
        const int* __restrict__ rank, int2* __restrict__ csr, int E) {
    const int e4 = (blockIdx.x * blockDim.x + threadIdx.x) * 4;
    if (e4 + 3 < E) {
        const int4 c4 = *reinterpret_cast<const int4*>(col + e4);
        const int4 r4 = *reinterpret_cast<const int4*>(row + e4);
        const int4 w4 = *reinterpret_cast<const int4*>((const int*)ew + e4);
        const int4 k4 = *reinterpret_cast<const int4*>(rank + e4);
        const int p0 = rowptr[c4.x] + k4.x;
        const int p1 = rowptr[c4.y] + k4.y;
        const int p2 = rowptr[c4.z] + k4.z;
        const int p3 = rowptr[c4.w] + k4.w;
        csr[p0] = make_int2(r4.x, w4.x);
        csr[p1] = make_int2(r4.y, w4.y);
        csr[p2] = make_int2(r4.z, w4.z);
        csr[p3] = make_int2(r4.w, w4.w);
    } else {
        for (int e = e4; e < E; e++)
            csr[rowptr[col[e]] + rank[e]] = make_int2(row[e], __float_as_int(ew[e]));
    }
}

// ======== dinv[n] = rsqrt(1 + sum ew) ========
__global__ __launch_bounds__(256) void degsum_kernel(
        const int* __restrict__ rowptr, const int2* __restrict__ csr,
        float* __restrict__ dinv, int N) {
    const int n = blockIdx.x * blockDim.x + threadIdx.x;
    if (n >= N) return;
    const int e0 = rowptr[n], e1 = rowptr[n + 1];
    float d = 1.0f;
    for (int e = e0; e < e1; e++) d += __int_as_float(csr[e].y);
    dinv[n] = (d > 0.0f) ? rsqrtf(d) : 0.0f;
}

// ======== agg1: Hb = relu(Ahat@Ab + b1); 16 lanes/node, 4-wide MLP ========
__global__ __launch_bounds__(256) void agg1_kernel(
        const int* __restrict__ rowptr, const int2* __restrict__ csr,
        const float* __restrict__ dinv,
        const ushort* __restrict__ src, const float* __restrict__ bias,
        ushort* __restrict__ dst, int N) {
    const int gid = blockIdx.x * 256 + threadIdx.x;
    const int c = gid >> 4;
    if (c >= N) return;
    const int lane = gid & 15;
    const float di = dinv[c];
    const float sl = di * di;
    float acc[8];
    {
        const short8 s8 = *reinterpret_cast<const short8*>(src + (size_t)c * 128 + lane * 8);
        #pragma unroll
        for (int j = 0; j < 8; j++) acc[j] = bf2f((ushort)s8[j]) * sl;
    }
    const int e0 = rowptr[c], e1 = rowptr[c + 1];
    int e = e0;
    for (; e + 4 <= e1; e += 4) {
        const int2 c0 = csr[e], c1 = csr[e + 1], c2 = csr[e + 2], c3 = csr[e + 3];
        const float w0 = __int_as_float(c0.y) * dinv[c0.x] * di;
        const float w1 = __int_as_float(c1.y) * dinv[c1.x] * di;
        const float w2 = __int_as_float(c2.y) * dinv[c2.x] * di;
        const float w3 = __int_as_float(c3.y) * dinv[c3.x] * di;
        const short8 v0 = *reinterpret_cast<const short8*>(src + (size_t)c0.x * 128 + lane * 8);
        const short8 v1 = *reinterpret_cast<const short8*>(src + (size_t)c1.x * 128 + lane * 8);
        const short8 v2 = *reinterpret_cast<const short8*>(src + (size_t)c2.x * 128 + lane * 8);
        const short8 v3 = *reinterpret_cast<const short8*>(src + (size_t)c3.x * 128 + lane * 8);
        #pragma unroll
        for (int j = 0; j < 8; j++)
            acc[j] += bf2f((ushort)v0[j]) * w0 + bf2f((ushort)v1[j]) * w1 +
                      bf2f((ushort)v2[j]) * w2 + bf2f((ushort)v3[j]) * w3;
    }
    for (; e < e1; e++) {
        const int2 ce = csr[e];
        const float w = __int_as_float(ce.y) * dinv[ce.x] * di;
        const short8 v = *reinterpret_cast<const short8*>(src + (size_t)ce.x * 128 + lane * 8);
        #pragma unroll
        for (int j = 0; j < 8; j++) acc[j] += bf2f((ushort)v[j]) * w;
    }
    const float4 b0 = reinterpret_cast<const float4*>(bias)[lane * 2];
    const float4 b1 = reinterpret_cast<const float4*>(bias)[lane * 2 + 1];
    acc[0] = fmaxf(acc[0] + b0.x, 0.f); acc[1] = fmaxf(acc[1] + b0.y, 0.f);
    acc[2] = fmaxf(acc[2] + b0.z, 0.f); acc[3] = fmaxf(acc[3] + b0.w, 0.f);
    acc[4] = fmaxf(acc[4] + b1.x, 0.f); acc[5] = fmaxf(acc[5] + b1.y, 0.f);
    acc[6] = fmaxf(acc[6] + b1.z, 0.f); acc[7] = fmaxf(acc[7] + b1.w, 0.f);
    uint4 o;
    o.x = (uint)f2bf(acc[0]) | ((uint)f2bf(acc[1]) << 16);
    o.y = (uint)f2bf(acc[2]) | ((uint)f2bf(acc[3]) << 16);
    o.z = (uint)f2bf(acc[4]) | ((uint)f2bf(acc[5]) << 16);
    o.w = (uint)f2bf(acc[6]) | ((uint)f2bf(acc[7]) << 16);
    *reinterpret_cast<uint4*>(dst + (size_t)c * 128 + lane * 8) = o;
}

// ======== gemm2: Gb = bf16(Hb @ W2t^T), DOUT=64 ========
__global__ __launch_bounds__(256, 2) void gemm2_kernel(
        const ushort* __restrict__ Xb, const ushort* __restrict__ Wt,
        ushort* __restrict__ Y, int N) {
    __shared__ __align__(16) ushort sX[128 * 128];
    __shared__ __align__(16) ushort sW[64 * 128];
    const int tid = threadIdx.x;
    const int base = blockIdx.x * 128;

    #pragma unroll
    for (int p = 0; p < 8; p++) {
        const int ch = p * 256 + tid;
        const int r = ch >> 4, cpos = ch & 15;
        const int grow = base + r;
        uint4 v = make_uint4(0, 0, 0, 0);
        if (grow < N)
            v = *reinterpret_cast<const uint4*>(Xb + (size_t)grow * 128 + cpos * 8);
        const int b = (cpos * 16) ^ ((r & 7) << 4);
        *reinterpret_cast<uint4*>(reinterpret_cast<char*>(sX) + r * 256 + b) = v;
    }
    #pragma unroll
    for (int p = 0; p < 4; p++) {
        const int ch = p * 256 + tid;
        const int r = ch >> 4, cpos = ch & 15;
        uint4 v = *reinterpret_cast<const uint4*>(Wt + (size_t)r * 128 + cpos * 8);
        const int b = (cpos * 16) ^ ((r & 7) << 4);
        *reinterpret_cast<uint4*>(reinterpret_cast<char*>(sW) + r * 256 + b) = v;
    }
    __syncthreads();

    const int lane = tid & 63;
    const int wid = tid >> 6;              // 4 row-waves, 1 col-wave
    const int lr = lane & 15;
    const int g  = lane >> 4;

    f32x4 acc[2][4];
    #pragma unroll
    for (int i = 0; i < 2; i++)
        #pragma unroll
        for (int f = 0; f < 4; f++) acc[i][f] = (f32x4){0.f, 0.f, 0.f, 0.f};

    #pragma unroll
    for (int ks = 0; ks < 4; ks++) {
        const int koff = ks * 64 + g * 16;
        short8 a[2], b[4];
        #pragma unroll
        for (int i = 0; i < 2; i++) {
            const int r = wid * 32 + i * 16 + lr;
            a[i] = *reinterpret_cast<const short8*>(
                reinterpret_cast<const char*>(sX) + r * 256 + (koff ^ ((r & 7) << 4)));
        }
        #pragma unroll
        for (int f = 0; f < 4; f++) {
            const int c = f * 16 + lr;
            b[f] = *reinterpret_cast<const short8*>(
                reinterpret_cast<const char*>(sW) + c * 256 + (koff ^ ((c & 7) << 4)));
        }
        #pragma unroll
        for (int i = 0; i < 2; i++)
            #pragma unroll
            for (int f = 0; f < 4; f++)
                acc[i][f] = __builtin_amdgcn_mfma_f32_16x16x32_bf16(a[i], b[f], acc[i][f], 0, 0, 0);
    }

    #pragma unroll
    for (int i = 0; i < 2; i++)
        #pragma unroll
        for (int reg = 0; reg < 4; reg++) {
            const int grow = base + wid * 32 + i * 16 + g * 4 + reg;
            if (grow < N)
                #pragma unroll
                for (int f = 0; f < 4; f++)
                    Y[(size_t)grow * 64 + f * 16 + lr] = f2bf(acc[i][f][reg]);
        }
}

// ======== agg2: out f32 = Ahat @ Gb + b2 (8 lanes/node) ========
__global__ __launch_bounds__(256) void agg2_kernel(
        const int* __restrict__ rowptr, const int2* __restrict__ csr,
        const float* __restrict__ dinv,
        const ushort* __restrict__ src, const float* __restrict__ bias,
        float* __restrict__ dst, int N) {
    const int gid = blockIdx.x * 256 + threadIdx.x;
    const int c = gid >> 3;
    if (c >= N) return;
    const int lane = gid & 7;
    const float di = dinv[c];
    const float sl = di * di;
    float acc[8];
    {
        const short8 s8 = *reinterpret_cast<const short8*>(src + (size_t)c * 64 + lane * 8);
        #pragma unroll
        for (int j = 0; j < 8; j++) acc[j] = bf2f((ushort)s8[j]) * sl;
    }
    const int e0 = rowptr[c], e1 = rowptr[c + 1];
    int e = e0;
    for (; e + 4 <= e1; e += 4) {
        const int2 c0 = csr[e], c1 = csr[e + 1], c2 = csr[e + 2], c3 = csr[e + 3];
        const float w0 = __int_as_float(c0.y) * dinv[c0.x] * di;
        const float w1 = __int_as_float(c1.y) * dinv[c1.x] * di;
        const float w2 = __int_as_float(c2.y) * dinv[c2.x] * di;
        const float w3 = __int_as_float(c3.y) * dinv[c3.x] * di;
        const short8 v0 = *reinterpret_cast<const short8*>(src + (size_t)c0.x * 64 + lane * 8);
        const short8 v1 = *reinterpret_cast<const short8*>(src + (size_t)c1.x * 64 + lane * 8);
        const short8 v2 = *reinterpret_cast<const short8*>(src + (size_t)c2.x * 64 + lane * 8);
        const short8 v3 = *reinterpret_cast<const short8*>(src + (size_t)c3.x * 64 + lane * 8);
        #pragma unroll
        for (int j = 0; j < 8; j++)
            acc[j] += bf2f((ushort)v0[j]) * w0 + bf2f((ushort)v1[j]) * w1 +
                      bf2f((ushort)v2[j]) * w2 + bf2f((ushort)v3[j]) * w3;
    }
    for (; e < e1; e++) {
        const int2 ce = csr[e];
        const float w = __int_as_float(ce.y) * dinv[ce.x] * di;
        const short8 v = *reinterpret_cast<const short8*>(src + (size_t)ce.x * 64 + lane * 8);
        #pragma unroll
        for (int j = 0; j < 8; j++) acc[j] += bf2f((ushort)v[j]) * w;
    }
    const float4 b0 = reinterpret_cast<const float4*>(bias)[lane * 2];
    const float4 b1 = reinterpret_cast<const float4*>(bias)[lane * 2 + 1];
    float* dp = dst + (size_t)c * 64 + lane * 8;
    *reinterpret_cast<float4*>(dp) =
        make_float4(acc[0] + b0.x, acc[1] + b0.y, acc[2] + b0.z, acc[3] + b0.w);
    *reinterpret_cast<float4*>(dp + 4) =
        make_float4(acc[4] + b1.x, acc[5] + b1.y, acc[6] + b1.z, acc[7] + b1.w);
}

extern "C" void kernel_launch(void* const* d_in, const int* in_sizes, int n_in,
                              void* d_out, int out_size, void* d_ws, size_t ws_size,
                              hipStream_t stream) {
    const float* x  = (const float*)d_in[0];
    const int*   ei = (const int*)d_in[1];
    const float* ew = (const float*)d_in[2];
    const float* W1 = (const float*)d_in[3];
    const float* b1 = (const float*)d_in[4];
    const float* W2 = (const float*)d_in[5];
    const float* b2 = (const float*)d_in[6];
    const int N = in_sizes[0] / 128;
    const int E = in_sizes[1] / 2;
    const int* row = ei;
    const int* col = ei + E;

    char* w = (char*)d_ws;
    float* dinv = (float*)w;                 w += (size_t)N * 4;
    ushort* Ab  = (ushort*)w;                w += (size_t)N * 256;  // bf16 xw
    ushort* Hb  = (ushort*)w;                w += (size_t)N * 256;  // bf16 h
    ushort* Gb  = (ushort*)w;                w += (size_t)N * 128;  // bf16 hw
    ushort* W2t = (ushort*)w;                w += 64 * 128 * 2;
    int* cnt    = (int*)w;                   w += (size_t)N * 4 + 16;
    int* rowptr = (int*)w;                   w += (size_t)(N + 8) * 4;
    int* partial= (int*)w;                   w += 2048 * 4;
    int* rank   = (int*)w;                   w += (size_t)E * 4;
    int2* csr   = (int2*)w;
    float* out  = (float*)d_out;

    const int ntiles = (N + 127) / 128;
    const int nbz = ((N >> 2) + 1 + 255) / 256;
    const int eb4 = (E / 4 + 255) / 256;

    gemm1_kernel<<<ntiles + nbz + 32, 256, 0, stream>>>(x, W1, Ab, N, ntiles,
                                                        cnt, W2, W2t);
    cnt_kernel<<<eb4, 256, 0, stream>>>(col, cnt, rank, E);
    scan_part_kernel<<<SCAN_BLOCKS, 256, 0, stream>>>(cnt, partial, N);
    scan_write_kernel<<<SCAN_BLOCKS, 256, 0, stream>>>(cnt, partial, rowptr, N, E);
    fill_kernel<<<eb4, 256, 0, stream>>>(row, col, ew, rowptr, rank, csr, E);
    degsum_kernel<<<(N + 255) / 256, 256, 0, stream>>>(rowptr, csr, dinv, N);
    agg1_kernel<<<(N * 16 + 255) / 256, 256, 0, stream>>>(rowptr, csr, dinv, Ab, b1, Hb, N);
    gemm2_kernel<<<ntiles, 256, 0, stream>>>(Hb, W2t, Gb, N);
    agg2_kernel<<<(N * 8 + 255) / 256, 256, 0, stream>>>(rowptr, csr, dinv, Gb, b2, out, N);
}